// Round 5
// baseline (145.855 us; speedup 1.0000x reference)
//
#include <hip/hip_runtime.h>
#include <hip/hip_bf16.h>
#include <cstdint>

typedef __attribute__((ext_vector_type(4))) float f32x4;
typedef __attribute__((ext_vector_type(8))) short s16x8;

#define NB   32
#define NL   2048
#define NH   512
#define NM   (NB * NL)          // 65536 rows
#define SCALE 0.04419417382415922f  // 1/sqrt(512)

__device__ __forceinline__ ushort f2bf(float f) {
    __hip_bfloat16 b = __float2bfloat16(f);   // pairs fuse into v_cvt_pk_bf16_f32
    return *reinterpret_cast<ushort*>(&b);
}
__device__ __forceinline__ float bf2f(unsigned u) {
    union { unsigned u; float f; } a; a.u = u << 16; return a.f;
}

// async global->LDS, 16B per lane, dest = wave-uniform base + lane*16
__device__ __forceinline__ void gl16(const ushort* g, ushort* l) {
    __builtin_amdgcn_global_load_lds(
        (const __attribute__((address_space(1))) unsigned int*)g,
        (__attribute__((address_space(3))) unsigned int*)l,
        16, 0, 0);
}

// ---- convert W_ref (512x512 f32) to bf16 ----
__global__ __launch_bounds__(256) void k_convW(const float* __restrict__ W,
                                               ushort* __restrict__ Wb) {
    int i = blockIdx.x * 256 + threadIdx.x;        // 32768 threads, 8 f32 each
    const float4* s = (const float4*)W;
    float4 a = s[2 * i], c = s[2 * i + 1];
    union { ushort u[8]; int4 v; } p;
    p.u[0] = f2bf(a.x); p.u[1] = f2bf(a.y); p.u[2] = f2bf(a.z); p.u[3] = f2bf(a.w);
    p.u[4] = f2bf(c.x); p.u[5] = f2bf(c.y); p.u[6] = f2bf(c.z); p.u[7] = f2bf(c.w);
    ((int4*)Wb)[i] = p.v;
}

// ---- convert ref (32x2048x512 f32) to bf16 ---- HBM-bound
__global__ __launch_bounds__(256) void k_convRef(const float* __restrict__ ref,
                                                 ushort* __restrict__ refb) {
    int i = blockIdx.x * 256 + threadIdx.x;        // 524288 threads
    const float4* s = (const float4*)ref;
#pragma unroll
    for (int it = 0; it < 8; ++it) {               // 8 x 8 f32 each = NM*NH
        int idx = it * 4194304 / 8 * 2;            // = it * 1048576 (in float4 units... see below)
        // simpler: element-chunk index
        int ci = i + it * 524288;                  // float4-pair index, 4194304 total
        float4 a = s[2 * ci], c = s[2 * ci + 1];
        union { ushort u[8]; int4 v; } p;
        p.u[0] = f2bf(a.x); p.u[1] = f2bf(a.y); p.u[2] = f2bf(a.z); p.u[3] = f2bf(a.w);
        p.u[4] = f2bf(c.x); p.u[5] = f2bf(c.y); p.u[6] = f2bf(c.z); p.u[7] = f2bf(c.w);
        ((int4*)refb)[ci] = p.v;
        (void)idx;
    }
}

// ---- eq[b][o] = dot(query[b,:], W_q[o,:]) ----
__global__ __launch_bounds__(512) void k_eq(const float* __restrict__ query,
                                            const float* __restrict__ Wq,
                                            float* __restrict__ eq) {
    int b = blockIdx.x;
    int o = threadIdx.x;
    __shared__ float q[NH];
    q[o] = query[b * NH + o];
    __syncthreads();
    const float4* w = (const float4*)(Wq + (size_t)o * NH);
    float acc = 0.f;
#pragma unroll 4
    for (int i = 0; i < NH / 4; ++i) {
        float4 x = w[i];
        acc += q[4 * i] * x.x + q[4 * i + 1] * x.y + q[4 * i + 2] * x.z + q[4 * i + 3] * x.w;
    }
    eq[b * NH + o] = acc;
}

// ============================================================================
// MAIN PATH: bf16 GEMM with global_load_lds direct staging.
// Tile 128x128, BK=32, 4 waves (2x2), 4x4 frags/wave, dbuf LDS [2][128][32],
// ONE barrier per K-step (T3 minimum 2-phase).
// ============================================================================
__global__ __launch_bounds__(256) void k_gemm_bf(const ushort* __restrict__ refb,
                                                 const ushort* __restrict__ Wb,
                                                 const float* __restrict__ eq,
                                                 const float* __restrict__ v,
                                                 float* __restrict__ part) {
    __shared__ ushort As[2][128 * 32];
    __shared__ ushort Bs[2][128 * 32];

    int tid = threadIdx.x;
    int lane = tid & 63, wid = tid >> 6;
    int wr = wid >> 1, wc = wid & 1;

    // XCD-aware swizzle: the 4 n-tiles of one m-tile land on the same XCD
    int phys = blockIdx.x;
    int xcd = phys & 7, slot = phys >> 3;         // 8 XCDs x 256 slots
    int mt = xcd * 64 + (slot >> 2);              // 512 m-tiles
    int nt = slot & 3;                            // 4 n-tiles
    int m0 = mt * 128, n0 = nt * 128;
    int b = mt >> 4;                              // 16 m-tiles per batch

    f32x4 acc[4][4];
#pragma unroll
    for (int i = 0; i < 4; ++i)
#pragma unroll
        for (int j = 0; j < 4; ++j) acc[i][j] = (f32x4)(0.f);

    // staging map: wave wid stages chunks cc=wid*2, wid*2+1 (16 rows each).
    // lane l writes 16B at lds chunk_base + l*16  <=>  row cc*16 + l/4, col (l%4)*8
    int cc = wid * 2;
    int grow = lane >> 2, gcol = (lane & 3) * 8;
    const ushort* aglob = refb + (size_t)(m0 + cc * 16 + grow) * NH + gcol;
    const ushort* bglob = Wb + (size_t)(n0 + cc * 16 + grow) * NH + gcol;

    int lr = lane & 15, kq = lane >> 4;
    int aoff[4], boff[4];
#pragma unroll
    for (int f = 0; f < 4; ++f) {
        aoff[f] = (wr * 64 + f * 16 + lr) * 32 + kq * 8;
        boff[f] = (wc * 64 + f * 16 + lr) * 32 + kq * 8;
    }

#define STAGE(buf, kt)                                      \
    {   gl16(aglob + (kt) * 32, &As[buf][cc * 512]);        \
        gl16(aglob + (kt) * 32 + 16 * NH, &As[buf][(cc + 1) * 512]); \
        gl16(bglob + (kt) * 32, &Bs[buf][cc * 512]);        \
        gl16(bglob + (kt) * 32 + 16 * NH, &Bs[buf][(cc + 1) * 512]); }

#define READ_FRAGS(buf)                                     \
    _Pragma("unroll")                                       \
    for (int f = 0; f < 4; ++f) af[f] = *(const s16x8*)&As[buf][aoff[f]]; \
    _Pragma("unroll")                                       \
    for (int f = 0; f < 4; ++f) bfr[f] = *(const s16x8*)&Bs[buf][boff[f]];

#define DO_MFMA()                                           \
    _Pragma("unroll")                                       \
    for (int fr = 0; fr < 4; ++fr)                          \
        _Pragma("unroll")                                   \
        for (int fc = 0; fc < 4; ++fc)                      \
            acc[fr][fc] = __builtin_amdgcn_mfma_f32_16x16x32_bf16(af[fr], bfr[fc], acc[fr][fc], 0, 0, 0);

    // prologue: tile 0 -> buf0
    STAGE(0, 0)
    __syncthreads();          // drains vmcnt(0)

    for (int t2 = 0; t2 < 8; ++t2) {
        s16x8 af[4], bfr[4];
        int k0 = 2 * t2;
        // phase A: stage kt=k0+1 -> buf1 (in flight across this phase); compute kt=k0 from buf0
        if (k0 + 1 < 16) STAGE(1, k0 + 1)
        READ_FRAGS(0)
        DO_MFMA()
        __syncthreads();
        // phase B: stage kt=k0+2 -> buf0; compute kt=k0+1 from buf1
        if (k0 + 2 < 16) STAGE(0, k0 + 2)
        READ_FRAGS(1)
        DO_MFMA()
        __syncthreads();
    }
#undef STAGE
#undef READ_FRAGS
#undef DO_MFMA

    // epilogue: partial score = sum_{o in tile} v[o]*tanh(e + eq[b][o])
    const float* eqb = eq + b * NH;
    float vv[4], ee[4];
#pragma unroll
    for (int fc = 0; fc < 4; ++fc) {
        int c = n0 + wc * 64 + fc * 16 + lr;
        vv[fc] = v[c];
        ee[fc] = eqb[c];
    }
#pragma unroll
    for (int fr = 0; fr < 4; ++fr) {
#pragma unroll
        for (int reg = 0; reg < 4; ++reg) {
            float s = 0.f;
#pragma unroll
            for (int fc = 0; fc < 4; ++fc) {
                float x = acc[fr][fc][reg] + ee[fc];
                float t = 1.f - 2.f / (__expf(2.f * x) + 1.f);  // tanh
                s += vv[fc] * t;
            }
            s += __shfl_xor(s, 1);
            s += __shfl_xor(s, 2);
            s += __shfl_xor(s, 4);
            s += __shfl_xor(s, 8);
            if (lr == 0) {
                int row = wr * 64 + fr * 16 + kq * 4 + reg;
                part[(size_t)nt * NM + m0 + row] = s;
            }
        }
    }
}

// ============================================================================
// FALLBACK PATH (ws too small): R2-proven reg-staged f32 GEMM
// ============================================================================
#define LDST 36
__global__ __launch_bounds__(256) void k_gemm_f32(const float* __restrict__ ref,
                                                  const ushort* __restrict__ Wb,
                                                  const float* __restrict__ eq,
                                                  const float* __restrict__ v,
                                                  float* __restrict__ part) {
    __shared__ ushort As[128 * LDST];
    __shared__ ushort Bs[128 * LDST];
    int tid = threadIdx.x;
    int lane = tid & 63, wid = tid >> 6;
    int wr = wid >> 1, wc = wid & 1;
    int phys = blockIdx.x;
    int xcd = phys & 7, slot = phys >> 3;
    int mt = xcd * 64 + (slot >> 2);
    int nt = slot & 3;
    int m0 = mt * 128, n0 = nt * 128;
    int b = mt >> 4;
    f32x4 acc[4][4];
#pragma unroll
    for (int i = 0; i < 4; ++i)
#pragma unroll
        for (int j = 0; j < 4; ++j) acc[i][j] = (f32x4)(0.f);
    int srow = tid >> 1, sks = (tid & 1) * 16;
    const float*  asrc = ref + (size_t)(m0 + srow) * NH + sks;
    const ushort* bsrc = Wb + (size_t)(n0 + srow) * NH + sks;
    int awr = srow * LDST + sks;
    int lr = lane & 15, kq = lane >> 4;
    int aoff[4], boff[4];
#pragma unroll
    for (int f = 0; f < 4; ++f) {
        aoff[f] = (wr * 64 + f * 16 + lr) * LDST + kq * 8;
        boff[f] = (wc * 64 + f * 16 + lr) * LDST + kq * 8;
    }
    float4 pa0, pa1, pa2, pa3;
    int4 pb0, pb1;
    {
        const float* s = asrc;
        pa0 = *(const float4*)(s); pa1 = *(const float4*)(s + 4);
        pa2 = *(const float4*)(s + 8); pa3 = *(const float4*)(s + 12);
        const int4* bs = (const int4*)(bsrc);
        pb0 = bs[0]; pb1 = bs[1];
    }
    for (int kt = 0; kt < 16; ++kt) {
        union { ushort u[8]; int4 v; } p0, p1;
        p0.u[0] = f2bf(pa0.x); p0.u[1] = f2bf(pa0.y); p0.u[2] = f2bf(pa0.z); p0.u[3] = f2bf(pa0.w);
        p0.u[4] = f2bf(pa1.x); p0.u[5] = f2bf(pa1.y); p0.u[6] = f2bf(pa1.z); p0.u[7] = f2bf(pa1.w);
        p1.u[0] = f2bf(pa2.x); p1.u[1] = f2bf(pa2.y); p1.u[2] = f2bf(pa2.z); p1.u[3] = f2bf(pa2.w);
        p1.u[4] = f2bf(pa3.x); p1.u[5] = f2bf(pa3.y); p1.u[6] = f2bf(pa3.z); p1.u[7] = f2bf(pa3.w);
        *(int4*)&As[awr] = p0.v; *(int4*)&As[awr + 8] = p1.v;
        *(int4*)&Bs[awr] = pb0;  *(int4*)&Bs[awr + 8] = pb1;
        __syncthreads();
        if (kt < 15) {
            const float* s = asrc + (kt + 1) * 32;
            pa0 = *(const float4*)(s); pa1 = *(const float4*)(s + 4);
            pa2 = *(const float4*)(s + 8); pa3 = *(const float4*)(s + 12);
            const int4* bs = (const int4*)(bsrc + (kt + 1) * 32);
            pb0 = bs[0]; pb1 = bs[1];
        }
        s16x8 af[4], bfr[4];
#pragma unroll
        for (int f = 0; f < 4; ++f) af[f] = *(const s16x8*)&As[aoff[f]];
#pragma unroll
        for (int f = 0; f < 4; ++f) bfr[f] = *(const s16x8*)&Bs[boff[f]];
        __syncthreads();
#pragma unroll
        for (int fr = 0; fr < 4; ++fr)
#pragma unroll
            for (int fc = 0; fc < 4; ++fc)
                acc[fr][fc] = __builtin_amdgcn_mfma_f32_16x16x32_bf16(af[fr], bfr[fc], acc[fr][fc], 0, 0, 0);
    }
    const float* eqb = eq + b * NH;
    float vv[4], ee[4];
#pragma unroll
    for (int fc = 0; fc < 4; ++fc) {
        int c = n0 + wc * 64 + fc * 16 + lr;
        vv[fc] = v[c]; ee[fc] = eqb[c];
    }
#pragma unroll
    for (int fr = 0; fr < 4; ++fr) {
#pragma unroll
        for (int reg = 0; reg < 4; ++reg) {
            float s = 0.f;
#pragma unroll
            for (int fc = 0; fc < 4; ++fc) {
                float x = acc[fr][fc][reg] + ee[fc];
                float t = 1.f - 2.f / (__expf(2.f * x) + 1.f);
                s += vv[fc] * t;
            }
            s += __shfl_xor(s, 1); s += __shfl_xor(s, 2);
            s += __shfl_xor(s, 4); s += __shfl_xor(s, 8);
            if (lr == 0) {
                int row = wr * 64 + fr * 16 + kq * 4 + reg;
                part[(size_t)nt * NM + m0 + row] = s;
            }
        }
    }
}

// ---- per-batch: combine partials, mask, write scores, softmax -> attn ----
__global__ __launch_bounds__(256) void k_softmax(const float* __restrict__ part,
                                                 const int* __restrict__ mask,
                                                 float* __restrict__ out_sc,
                                                 float* __restrict__ attn) {
    int b = blockIdx.x;
    int tid = threadIdx.x;
    int lane = tid & 63, wid = tid >> 6;
    __shared__ float red[4];
    float sc[8];
    float mx = -3.4e38f;
#pragma unroll
    for (int i = 0; i < 8; ++i) {
        int m = b * NL + i * 256 + tid;
        float s = (part[m] + part[NM + m] + part[2 * NM + m] + part[3 * NM + m]) * SCALE;
        if (mask[m] != 0) s = -1e9f;
        out_sc[m] = s;
        sc[i] = s;
        mx = fmaxf(mx, s);
    }
#pragma unroll
    for (int o = 32; o >= 1; o >>= 1) mx = fmaxf(mx, __shfl_xor(mx, o));
    if (lane == 0) red[wid] = mx;
    __syncthreads();
    mx = fmaxf(fmaxf(red[0], red[1]), fmaxf(red[2], red[3]));
    __syncthreads();
    float ls = 0.f;
#pragma unroll
    for (int i = 0; i < 8; ++i) {
        float e = __expf(sc[i] - mx);
        sc[i] = e;
        ls += e;
    }
#pragma unroll
    for (int o = 32; o >= 1; o >>= 1) ls += __shfl_xor(ls, o);
    if (lane == 0) red[wid] = ls;
    __syncthreads();
    float inv = 1.f / (red[0] + red[1] + red[2] + red[3]);
#pragma unroll
    for (int i = 0; i < 8; ++i) attn[b * NL + i * 256 + tid] = sc[i] * inv;
}

// ---- glimpse partials from bf16 ref ----
__global__ __launch_bounds__(256) void k_glp_bf(const ushort* __restrict__ refb,
                                                const float* __restrict__ attn,
                                                float* __restrict__ glp) {
    int sp = blockIdx.x, b = blockIdx.y;
    int tid = threadIdx.x;
    const float* attb = attn + b * NL + sp * 128;
    float2 acc = make_float2(0.f, 0.f);
#pragma unroll 4
    for (int l = 0; l < 128; ++l) {
        float a = attb[l];
        unsigned r = ((const unsigned*)(refb + (size_t)(b * NL + sp * 128 + l) * NH))[tid];
        acc.x += a * bf2f(r & 0xFFFFu);
        acc.y += a * bf2f(r >> 16);
    }
    ((float2*)(glp + (size_t)(sp * NB + b) * NH))[tid] = acc;
}

// ---- glimpse partials from f32 ref (fallback) ----
__global__ __launch_bounds__(256) void k_glp_f32(const float* __restrict__ ref,
                                                 const float* __restrict__ attn,
                                                 float* __restrict__ glp) {
    int sp = blockIdx.x, b = blockIdx.y;
    int tid = threadIdx.x;
    const float* attb = attn + b * NL + sp * 128;
    float2 acc = make_float2(0.f, 0.f);
#pragma unroll 4
    for (int l = 0; l < 128; ++l) {
        float a = attb[l];
        const float2* row = (const float2*)(ref + (size_t)(b * NL + sp * 128 + l) * NH);
        float2 r = row[tid];
        acc.x += a * r.x;
        acc.y += a * r.y;
    }
    ((float2*)(glp + (size_t)(sp * NB + b) * NH))[tid] = acc;
}

// ---- reduce glimpse partials ----
__global__ __launch_bounds__(256) void k_gred(const float* __restrict__ glp,
                                              float* __restrict__ out_gl) {
    int idx = blockIdx.x * 256 + threadIdx.x;   // 16384 = B*H
    float s = 0.f;
#pragma unroll
    for (int sp = 0; sp < 16; ++sp) s += glp[sp * (NB * NH) + idx];
    out_gl[idx] = s;
}

extern "C" void kernel_launch(void* const* d_in, const int* in_sizes, int n_in,
                              void* d_out, int out_size, void* d_ws, size_t ws_size,
                              hipStream_t stream) {
    const float* query = (const float*)d_in[0];
    const float* ref   = (const float*)d_in[1];
    const int*   mask  = (const int*)d_in[2];
    const float* W_ref = (const float*)d_in[3];
    const float* W_q   = (const float*)d_in[4];
    const float* v     = (const float*)d_in[5];

    float* out_gl = (float*)d_out;              // 32*512
    float* out_sc = out_gl + NB * NH;           // 32*2048

    char* w = (char*)d_ws;
    // common small buffers
    ushort* wW  = (ushort*)w;                   // 524288 B @ 0

    if (ws_size >= (size_t)70100000) {
        // MAIN PATH layout
        ushort* refb = (ushort*)(w + 524288);                 // 67,108,864 B
        float* eq    = (float*)(w + 524288 + 67108864);       // 65,536
        float* part  = (float*)(w + 524288 + 67108864 + 65536);           // 1,048,576
        float* attn  = (float*)(w + 524288 + 67108864 + 65536 + 1048576); // 262,144
        float* glp   = (float*)(w + 524288 + 67108864 + 65536 + 1048576 + 262144); // 1,048,576

        k_convW<<<128, 256, 0, stream>>>(W_ref, wW);
        k_convRef<<<2048, 256, 0, stream>>>(ref, refb);
        k_eq<<<NB, 512, 0, stream>>>(query, W_q, eq);
        k_gemm_bf<<<2048, 256, 0, stream>>>(refb, wW, eq, v, part);
        k_softmax<<<NB, 256, 0, stream>>>(part, mask, out_sc, attn);
        k_glp_bf<<<dim3(16, NB), 256, 0, stream>>>(refb, attn, glp);
        k_gred<<<64, 256, 0, stream>>>(glp, out_gl);
    } else {
        // FALLBACK PATH (R2-proven)
        float* eq   = (float*)(w + 524288);
        float* part = (float*)(w + 589824);
        float* attn = (float*)(w + 1638400);
        float* glp  = (float*)(w + 1900544);

        k_convW<<<128, 256, 0, stream>>>(W_ref, wW);
        k_eq<<<NB, 512, 0, stream>>>(query, W_q, eq);
        k_gemm_f32<<<2048, 256, 0, stream>>>(ref, wW, eq, v, part);
        k_softmax<<<NB, 256, 0, stream>>>(part, mask, out_sc, attn);
        k_glp_f32<<<dim3(16, NB), 256, 0, stream>>>(ref, attn, glp);
        k_gred<<<64, 256, 0, stream>>>(glp, out_gl);
    }
}

// Round 6
// 142.572 us; speedup vs baseline: 1.0230x; 1.0230x over previous
//
#include <hip/hip_runtime.h>
#include <hip/hip_bf16.h>
#include <cstdint>

typedef __attribute__((ext_vector_type(4))) float f32x4;
typedef __attribute__((ext_vector_type(8))) short s16x8;

#define NB   32
#define NL   2048
#define NH   512
#define NM   (NB * NL)          // 65536 rows
#define SCALE 0.04419417382415922f  // 1/sqrt(512)

__device__ __forceinline__ ushort f2bf(float f) {
    __hip_bfloat16 b = __float2bfloat16(f);   // pairs fuse into v_cvt_pk_bf16_f32
    return *reinterpret_cast<ushort*>(&b);
}
__device__ __forceinline__ float bf2f(unsigned u) {
    union { unsigned u; float f; } a; a.u = u << 16; return a.f;
}

// async global->LDS, 16B per lane, dest = wave-uniform base + lane*16
__device__ __forceinline__ void gl16(const ushort* g, ushort* l) {
    __builtin_amdgcn_global_load_lds(
        (const __attribute__((address_space(1))) unsigned int*)g,
        (__attribute__((address_space(3))) unsigned int*)l,
        16, 0, 0);
}

// ============================================================================
// k_prep: fused convRef (blocks 0..2047) + convW (2048..2175) + eq (2176..2207)
// ============================================================================
__global__ __launch_bounds__(256) void k_prep(const float* __restrict__ ref,
                                              ushort* __restrict__ refb,
                                              const float* __restrict__ W,
                                              ushort* __restrict__ Wb,
                                              const float* __restrict__ query,
                                              const float* __restrict__ Wq,
                                              float* __restrict__ eq) {
    int bid = blockIdx.x;
    if (bid < 2048) {
        // ---- ref f32 -> bf16: 2048 blocks x 256 thr x 8 iters x 8 f32 ----
        int i = bid * 256 + threadIdx.x;
        const float4* s = (const float4*)ref;
#pragma unroll
        for (int it = 0; it < 8; ++it) {
            int ci = i + it * 524288;              // float4-pair index, 4194304 total
            float4 a = s[2 * ci], c = s[2 * ci + 1];
            union { ushort u[8]; int4 v; } p;
            p.u[0] = f2bf(a.x); p.u[1] = f2bf(a.y); p.u[2] = f2bf(a.z); p.u[3] = f2bf(a.w);
            p.u[4] = f2bf(c.x); p.u[5] = f2bf(c.y); p.u[6] = f2bf(c.z); p.u[7] = f2bf(c.w);
            ((int4*)refb)[ci] = p.v;
        }
    } else if (bid < 2176) {
        // ---- W_ref f32 -> bf16: 128 blocks ----
        int i = (bid - 2048) * 256 + threadIdx.x;
        const float4* s = (const float4*)W;
        float4 a = s[2 * i], c = s[2 * i + 1];
        union { ushort u[8]; int4 v; } p;
        p.u[0] = f2bf(a.x); p.u[1] = f2bf(a.y); p.u[2] = f2bf(a.z); p.u[3] = f2bf(a.w);
        p.u[4] = f2bf(c.x); p.u[5] = f2bf(c.y); p.u[6] = f2bf(c.z); p.u[7] = f2bf(c.w);
        ((int4*)Wb)[i] = p.v;
    } else {
        // ---- eq[b][o] = dot(query[b,:], W_q[o,:]): 32 blocks, 2 o's/thread ----
        __shared__ float q[NH];
        int b = bid - 2176;
        int t = threadIdx.x;
        q[t] = query[b * NH + t];
        q[t + 256] = query[b * NH + t + 256];
        __syncthreads();
#pragma unroll
        for (int half = 0; half < 2; ++half) {
            int o = t + half * 256;
            const float4* w = (const float4*)(Wq + (size_t)o * NH);
            float acc = 0.f;
#pragma unroll 4
            for (int i = 0; i < NH / 4; ++i) {
                float4 x = w[i];
                acc += q[4 * i] * x.x + q[4 * i + 1] * x.y + q[4 * i + 2] * x.z + q[4 * i + 3] * x.w;
            }
            eq[b * NH + o] = acc;
        }
    }
}

// ============================================================================
// MAIN GEMM: bf16, global_load_lds staging, tile 128x128, BK=32, 4 waves (2x2),
// dbuf LDS [2][128][32], ONE barrier per K-step.
// ============================================================================
__global__ __launch_bounds__(256, 3) void k_gemm_bf(const ushort* __restrict__ refb,
                                                    const ushort* __restrict__ Wb,
                                                    const float* __restrict__ eq,
                                                    const float* __restrict__ v,
                                                    float* __restrict__ part) {
    __shared__ ushort As[2][128 * 32];
    __shared__ ushort Bs[2][128 * 32];

    int tid = threadIdx.x;
    int lane = tid & 63, wid = tid >> 6;
    int wr = wid >> 1, wc = wid & 1;

    // XCD-aware swizzle: the 4 n-tiles of one m-tile land on the same XCD
    int phys = blockIdx.x;
    int xcd = phys & 7, slot = phys >> 3;         // 8 XCDs x 256 slots
    int mt = xcd * 64 + (slot >> 2);              // 512 m-tiles
    int nt = slot & 3;                            // 4 n-tiles
    int m0 = mt * 128, n0 = nt * 128;
    int b = mt >> 4;                              // 16 m-tiles per batch

    f32x4 acc[4][4];
#pragma unroll
    for (int i = 0; i < 4; ++i)
#pragma unroll
        for (int j = 0; j < 4; ++j) acc[i][j] = (f32x4)(0.f);

    // staging map: wave wid stages chunks cc=wid*2, wid*2+1 (16 rows each).
    int cc = wid * 2;
    int grow = lane >> 2, gcol = (lane & 3) * 8;
    const ushort* aglob = refb + (size_t)(m0 + cc * 16 + grow) * NH + gcol;
    const ushort* bglob = Wb + (size_t)(n0 + cc * 16 + grow) * NH + gcol;

    int lr = lane & 15, kq = lane >> 4;
    int aoff[4], boff[4];
#pragma unroll
    for (int f = 0; f < 4; ++f) {
        aoff[f] = (wr * 64 + f * 16 + lr) * 32 + kq * 8;
        boff[f] = (wc * 64 + f * 16 + lr) * 32 + kq * 8;
    }

#define STAGE(buf, kt)                                      \
    {   gl16(aglob + (kt) * 32, &As[buf][cc * 512]);        \
        gl16(aglob + (kt) * 32 + 16 * NH, &As[buf][(cc + 1) * 512]); \
        gl16(bglob + (kt) * 32, &Bs[buf][cc * 512]);        \
        gl16(bglob + (kt) * 32 + 16 * NH, &Bs[buf][(cc + 1) * 512]); }

#define READ_FRAGS(buf)                                     \
    _Pragma("unroll")                                       \
    for (int f = 0; f < 4; ++f) af[f] = *(const s16x8*)&As[buf][aoff[f]]; \
    _Pragma("unroll")                                       \
    for (int f = 0; f < 4; ++f) bfr[f] = *(const s16x8*)&Bs[buf][boff[f]];

#define DO_MFMA()                                           \
    _Pragma("unroll")                                       \
    for (int fr = 0; fr < 4; ++fr)                          \
        _Pragma("unroll")                                   \
        for (int fc = 0; fc < 4; ++fc)                      \
            acc[fr][fc] = __builtin_amdgcn_mfma_f32_16x16x32_bf16(af[fr], bfr[fc], acc[fr][fc], 0, 0, 0);

    // prologue: tile 0 -> buf0
    STAGE(0, 0)
    __syncthreads();

    for (int t2 = 0; t2 < 8; ++t2) {
        s16x8 af[4], bfr[4];
        int k0 = 2 * t2;
        if (k0 + 1 < 16) STAGE(1, k0 + 1)
        READ_FRAGS(0)
        DO_MFMA()
        __syncthreads();
        if (k0 + 2 < 16) STAGE(0, k0 + 2)
        READ_FRAGS(1)
        DO_MFMA()
        __syncthreads();
    }
#undef STAGE
#undef READ_FRAGS
#undef DO_MFMA

    // epilogue: partial score = sum_{o in tile} v[o]*tanh(e + eq[b][o])
    const float* eqb = eq + b * NH;
    float vv[4], ee[4];
#pragma unroll
    for (int fc = 0; fc < 4; ++fc) {
        int c = n0 + wc * 64 + fc * 16 + lr;
        vv[fc] = v[c];
        ee[fc] = eqb[c];
    }
#pragma unroll
    for (int fr = 0; fr < 4; ++fr) {
#pragma unroll
        for (int reg = 0; reg < 4; ++reg) {
            float s = 0.f;
#pragma unroll
            for (int fc = 0; fc < 4; ++fc) {
                float x = acc[fr][fc][reg] + ee[fc];
                float t = 1.f - 2.f / (__expf(2.f * x) + 1.f);  // tanh
                s += vv[fc] * t;
            }
            s += __shfl_xor(s, 1);
            s += __shfl_xor(s, 2);
            s += __shfl_xor(s, 4);
            s += __shfl_xor(s, 8);
            if (lr == 0) {
                int row = wr * 64 + fr * 16 + kq * 4 + reg;
                part[(size_t)nt * NM + m0 + row] = s;
            }
        }
    }
}

// ============================================================================
// k_smglp: fused softmax + glimpse slice. grid (8 sp, 32 b).
// Every block recomputes the full-row softmax (part is tiny/L2-hot);
// sp==0 writes scores; each block computes glimpse for its 256 rows.
// ============================================================================
__global__ __launch_bounds__(256) void k_smglp(const float* __restrict__ part,
                                               const int* __restrict__ mask,
                                               const ushort* __restrict__ refb,
                                               float* __restrict__ out_sc,
                                               float* __restrict__ glp) {
    int sp = blockIdx.x, b = blockIdx.y;
    int tid = threadIdx.x;
    int lane = tid & 63, wid = tid >> 6;
    __shared__ float red[4];
    __shared__ float asl[256];    // unnormalized exp for rows sp*256..+255
    float sc[8];
    float mx = -3.4e38f;
#pragma unroll
    for (int i = 0; i < 8; ++i) {
        int m = b * NL + i * 256 + tid;
        float s = (part[m] + part[NM + m] + part[2 * NM + m] + part[3 * NM + m]) * SCALE;
        if (mask[m] != 0) s = -1e9f;
        if (sp == 0) out_sc[m] = s;
        sc[i] = s;
        mx = fmaxf(mx, s);
    }
#pragma unroll
    for (int o = 32; o >= 1; o >>= 1) mx = fmaxf(mx, __shfl_xor(mx, o));
    if (lane == 0) red[wid] = mx;
    __syncthreads();
    mx = fmaxf(fmaxf(red[0], red[1]), fmaxf(red[2], red[3]));
    __syncthreads();
    float ls = 0.f;
#pragma unroll
    for (int i = 0; i < 8; ++i) {
        float e = __expf(sc[i] - mx);
        ls += e;
        if (i == sp) asl[tid] = e;   // static i, runtime sp: no reg-array runtime index
    }
#pragma unroll
    for (int o = 32; o >= 1; o >>= 1) ls += __shfl_xor(ls, o);
    if (lane == 0) red[wid] = ls;
    __syncthreads();
    float inv = 1.f / (red[0] + red[1] + red[2] + red[3]);

    // glimpse over this block's 256 rows (refb rows b*NL + sp*256 ..)
    const ushort* rb = refb + ((size_t)b * NL + sp * 256) * NH;
    float2 acc = make_float2(0.f, 0.f);
#pragma unroll 4
    for (int l = 0; l < 256; ++l) {
        float a = asl[l];
        unsigned r = ((const unsigned*)(rb + (size_t)l * NH))[tid];
        acc.x += a * bf2f(r & 0xFFFFu);
        acc.y += a * bf2f(r >> 16);
    }
    acc.x *= inv;
    acc.y *= inv;
    ((float2*)(glp + (size_t)(sp * NB + b) * NH))[tid] = acc;
}

// ---- reduce glimpse partials (8 splits) ----
__global__ __launch_bounds__(256) void k_gred(const float* __restrict__ glp,
                                              float* __restrict__ out_gl) {
    int idx = blockIdx.x * 256 + threadIdx.x;   // 16384 = B*H
    float s = 0.f;
#pragma unroll
    for (int sp = 0; sp < 8; ++sp) s += glp[sp * (NB * NH) + idx];
    out_gl[idx] = s;
}

// ============================================================================
// FALLBACK PATH (ws too small): R2-proven reg-staged f32 GEMM + separate stages
// ============================================================================
#define LDST 36
__global__ __launch_bounds__(256) void k_convW_f(const float* __restrict__ W,
                                                 ushort* __restrict__ Wb) {
    int i = blockIdx.x * 256 + threadIdx.x;
    const float4* s = (const float4*)W;
    float4 a = s[2 * i], c = s[2 * i + 1];
    union { ushort u[8]; int4 v; } p;
    p.u[0] = f2bf(a.x); p.u[1] = f2bf(a.y); p.u[2] = f2bf(a.z); p.u[3] = f2bf(a.w);
    p.u[4] = f2bf(c.x); p.u[5] = f2bf(c.y); p.u[6] = f2bf(c.z); p.u[7] = f2bf(c.w);
    ((int4*)Wb)[i] = p.v;
}
__global__ __launch_bounds__(512) void k_eq_f(const float* __restrict__ query,
                                              const float* __restrict__ Wq,
                                              float* __restrict__ eq) {
    int b = blockIdx.x;
    int o = threadIdx.x;
    __shared__ float q[NH];
    q[o] = query[b * NH + o];
    __syncthreads();
    const float4* w = (const float4*)(Wq + (size_t)o * NH);
    float acc = 0.f;
#pragma unroll 4
    for (int i = 0; i < NH / 4; ++i) {
        float4 x = w[i];
        acc += q[4 * i] * x.x + q[4 * i + 1] * x.y + q[4 * i + 2] * x.z + q[4 * i + 3] * x.w;
    }
    eq[b * NH + o] = acc;
}
__global__ __launch_bounds__(256) void k_gemm_f32(const float* __restrict__ ref,
                                                  const ushort* __restrict__ Wb,
                                                  const float* __restrict__ eq,
                                                  const float* __restrict__ v,
                                                  float* __restrict__ part) {
    __shared__ ushort As[128 * LDST];
    __shared__ ushort Bs[128 * LDST];
    int tid = threadIdx.x;
    int lane = tid & 63, wid = tid >> 6;
    int wr = wid >> 1, wc = wid & 1;
    int phys = blockIdx.x;
    int xcd = phys & 7, slot = phys >> 3;
    int mt = xcd * 64 + (slot >> 2);
    int nt = slot & 3;
    int m0 = mt * 128, n0 = nt * 128;
    int b = mt >> 4;
    f32x4 acc[4][4];
#pragma unroll
    for (int i = 0; i < 4; ++i)
#pragma unroll
        for (int j = 0; j < 4; ++j) acc[i][j] = (f32x4)(0.f);
    int srow = tid >> 1, sks = (tid & 1) * 16;
    const float*  asrc = ref + (size_t)(m0 + srow) * NH + sks;
    const ushort* bsrc = Wb + (size_t)(n0 + srow) * NH + sks;
    int awr = srow * LDST + sks;
    int lr = lane & 15, kq = lane >> 4;
    int aoff[4], boff[4];
#pragma unroll
    for (int f = 0; f < 4; ++f) {
        aoff[f] = (wr * 64 + f * 16 + lr) * LDST + kq * 8;
        boff[f] = (wc * 64 + f * 16 + lr) * LDST + kq * 8;
    }
    float4 pa0, pa1, pa2, pa3;
    int4 pb0, pb1;
    {
        const float* s = asrc;
        pa0 = *(const float4*)(s); pa1 = *(const float4*)(s + 4);
        pa2 = *(const float4*)(s + 8); pa3 = *(const float4*)(s + 12);
        const int4* bs = (const int4*)(bsrc);
        pb0 = bs[0]; pb1 = bs[1];
    }
    for (int kt = 0; kt < 16; ++kt) {
        union { ushort u[8]; int4 v; } p0, p1;
        p0.u[0] = f2bf(pa0.x); p0.u[1] = f2bf(pa0.y); p0.u[2] = f2bf(pa0.z); p0.u[3] = f2bf(pa0.w);
        p0.u[4] = f2bf(pa1.x); p0.u[5] = f2bf(pa1.y); p0.u[6] = f2bf(pa1.z); p0.u[7] = f2bf(pa1.w);
        p1.u[0] = f2bf(pa2.x); p1.u[1] = f2bf(pa2.y); p1.u[2] = f2bf(pa2.z); p1.u[3] = f2bf(pa2.w);
        p1.u[4] = f2bf(pa3.x); p1.u[5] = f2bf(pa3.y); p1.u[6] = f2bf(pa3.z); p1.u[7] = f2bf(pa3.w);
        *(int4*)&As[awr] = p0.v; *(int4*)&As[awr + 8] = p1.v;
        *(int4*)&Bs[awr] = pb0;  *(int4*)&Bs[awr + 8] = pb1;
        __syncthreads();
        if (kt < 15) {
            const float* s = asrc + (kt + 1) * 32;
            pa0 = *(const float4*)(s); pa1 = *(const float4*)(s + 4);
            pa2 = *(const float4*)(s + 8); pa3 = *(const float4*)(s + 12);
            const int4* bs = (const int4*)(bsrc + (kt + 1) * 32);
            pb0 = bs[0]; pb1 = bs[1];
        }
        s16x8 af[4], bfr[4];
#pragma unroll
        for (int f = 0; f < 4; ++f) af[f] = *(const s16x8*)&As[aoff[f]];
#pragma unroll
        for (int f = 0; f < 4; ++f) bfr[f] = *(const s16x8*)&Bs[boff[f]];
        __syncthreads();
#pragma unroll
        for (int fr = 0; fr < 4; ++fr)
#pragma unroll
            for (int fc = 0; fc < 4; ++fc)
                acc[fr][fc] = __builtin_amdgcn_mfma_f32_16x16x32_bf16(af[fr], bfr[fc], acc[fr][fc], 0, 0, 0);
    }
    const float* eqb = eq + b * NH;
    float vv[4], ee[4];
#pragma unroll
    for (int fc = 0; fc < 4; ++fc) {
        int c = n0 + wc * 64 + fc * 16 + lr;
        vv[fc] = v[c]; ee[fc] = eqb[c];
    }
#pragma unroll
    for (int fr = 0; fr < 4; ++fr) {
#pragma unroll
        for (int reg = 0; reg < 4; ++reg) {
            float s = 0.f;
#pragma unroll
            for (int fc = 0; fc < 4; ++fc) {
                float x = acc[fr][fc][reg] + ee[fc];
                float t = 1.f - 2.f / (__expf(2.f * x) + 1.f);
                s += vv[fc] * t;
            }
            s += __shfl_xor(s, 1); s += __shfl_xor(s, 2);
            s += __shfl_xor(s, 4); s += __shfl_xor(s, 8);
            if (lr == 0) {
                int row = wr * 64 + fr * 16 + kq * 4 + reg;
                part[(size_t)nt * NM + m0 + row] = s;
            }
        }
    }
}
__global__ __launch_bounds__(256) void k_softmax_f(const float* __restrict__ part,
                                                   const int* __restrict__ mask,
                                                   float* __restrict__ out_sc,
                                                   float* __restrict__ attn) {
    int b = blockIdx.x;
    int tid = threadIdx.x;
    int lane = tid & 63, wid = tid >> 6;
    __shared__ float red[4];
    float sc[8];
    float mx = -3.4e38f;
#pragma unroll
    for (int i = 0; i < 8; ++i) {
        int m = b * NL + i * 256 + tid;
        float s = (part[m] + part[NM + m] + part[2 * NM + m] + part[3 * NM + m]) * SCALE;
        if (mask[m] != 0) s = -1e9f;
        out_sc[m] = s;
        sc[i] = s;
        mx = fmaxf(mx, s);
    }
#pragma unroll
    for (int o = 32; o >= 1; o >>= 1) mx = fmaxf(mx, __shfl_xor(mx, o));
    if (lane == 0) red[wid] = mx;
    __syncthreads();
    mx = fmaxf(fmaxf(red[0], red[1]), fmaxf(red[2], red[3]));
    __syncthreads();
    float ls = 0.f;
#pragma unroll
    for (int i = 0; i < 8; ++i) {
        float e = __expf(sc[i] - mx);
        sc[i] = e;
        ls += e;
    }
#pragma unroll
    for (int o = 32; o >= 1; o >>= 1) ls += __shfl_xor(ls, o);
    if (lane == 0) red[wid] = ls;
    __syncthreads();
    float inv = 1.f / (red[0] + red[1] + red[2] + red[3]);
#pragma unroll
    for (int i = 0; i < 8; ++i) attn[b * NL + i * 256 + tid] = sc[i] * inv;
}
__global__ __launch_bounds__(256) void k_glp_f32(const float* __restrict__ ref,
                                                 const float* __restrict__ attn,
                                                 float* __restrict__ glp) {
    int sp = blockIdx.x, b = blockIdx.y;
    int tid = threadIdx.x;
    const float* attb = attn + b * NL + sp * 128;
    float2 acc = make_float2(0.f, 0.f);
#pragma unroll 4
    for (int l = 0; l < 128; ++l) {
        float a = attb[l];
        const float2* row = (const float2*)(ref + (size_t)(b * NL + sp * 128 + l) * NH);
        float2 r = row[tid];
        acc.x += a * r.x;
        acc.y += a * r.y;
    }
    ((float2*)(glp + (size_t)(sp * NB + b) * NH))[tid] = acc;
}
__global__ __launch_bounds__(256) void k_gred16(const float* __restrict__ glp,
                                                float* __restrict__ out_gl) {
    int idx = blockIdx.x * 256 + threadIdx.x;
    float s = 0.f;
#pragma unroll
    for (int sp = 0; sp < 16; ++sp) s += glp[sp * (NB * NH) + idx];
    out_gl[idx] = s;
}

extern "C" void kernel_launch(void* const* d_in, const int* in_sizes, int n_in,
                              void* d_out, int out_size, void* d_ws, size_t ws_size,
                              hipStream_t stream) {
    const float* query = (const float*)d_in[0];
    const float* ref   = (const float*)d_in[1];
    const int*   mask  = (const int*)d_in[2];
    const float* W_ref = (const float*)d_in[3];
    const float* W_q   = (const float*)d_in[4];
    const float* v     = (const float*)d_in[5];

    float* out_gl = (float*)d_out;              // 32*512
    float* out_sc = out_gl + NB * NH;           // 32*2048

    char* w = (char*)d_ws;
    ushort* wW  = (ushort*)w;                   // 524288 B @ 0

    if (ws_size >= (size_t)70100000) {
        // MAIN PATH layout
        ushort* refb = (ushort*)(w + 524288);                              // 67,108,864 B
        float* eq    = (float*)(w + 524288 + 67108864);                    // 65,536
        float* part  = (float*)(w + 524288 + 67108864 + 65536);            // 1,048,576
        float* glp   = (float*)(w + 524288 + 67108864 + 65536 + 1048576);  // 524,288 (8 splits)

        k_prep<<<2208, 256, 0, stream>>>(ref, refb, W_ref, wW, query, W_q, eq);
        k_gemm_bf<<<2048, 256, 0, stream>>>(refb, wW, eq, v, part);
        k_smglp<<<dim3(8, NB), 256, 0, stream>>>(part, mask, refb, out_sc, glp);
        k_gred<<<64, 256, 0, stream>>>(glp, out_gl);
    } else {
        // FALLBACK PATH (R2-proven)
        float* eq   = (float*)(w + 524288);
        float* part = (float*)(w + 589824);
        float* attn = (float*)(w + 1638400);
        float* glp  = (float*)(w + 1900544);

        k_convW_f<<<128, 256, 0, stream>>>(W_ref, wW);
        k_eq_f<<<NB, 512, 0, stream>>>(query, W_q, eq);
        k_gemm_f32<<<2048, 256, 0, stream>>>(ref, wW, eq, v, part);
        k_softmax_f<<<NB, 256, 0, stream>>>(part, mask, out_sc, attn);
        k_glp_f32<<<dim3(16, NB), 256, 0, stream>>>(ref, attn, glp);
        k_gred16<<<64, 256, 0, stream>>>(glp, out_gl);
    }
}

// Round 7
// 140.914 us; speedup vs baseline: 1.0351x; 1.0118x over previous
//
#include <hip/hip_runtime.h>
#include <hip/hip_bf16.h>
#include <cstdint>

typedef __attribute__((ext_vector_type(4))) float f32x4;
typedef __attribute__((ext_vector_type(8))) short s16x8;

#define NB   32
#define NL   2048
#define NH   512
#define NM   (NB * NL)          // 65536 rows
#define SCALE 0.04419417382415922f  // 1/sqrt(512)

__device__ __forceinline__ ushort f2bf(float f) {
    __hip_bfloat16 b = __float2bfloat16(f);   // pairs fuse into v_cvt_pk_bf16_f32
    return *reinterpret_cast<ushort*>(&b);
}
__device__ __forceinline__ float bf2f(unsigned u) {
    union { unsigned u; float f; } a; a.u = u << 16; return a.f;
}
__device__ __forceinline__ unsigned long long pack4(float4 f) {
    union { ushort u[4]; unsigned long long v; } p;
    p.u[0] = f2bf(f.x); p.u[1] = f2bf(f.y); p.u[2] = f2bf(f.z); p.u[3] = f2bf(f.w);
    return p.v;
}

// async global->LDS, 16B per lane, dest = wave-uniform base + lane*16
__device__ __forceinline__ void gl16(const ushort* g, ushort* l) {
    __builtin_amdgcn_global_load_lds(
        (const __attribute__((address_space(1))) unsigned int*)g,
        (__attribute__((address_space(3))) unsigned int*)l,
        16, 0, 0);
}

// ============================================================================
// k_prep: fused convRef (blocks 0..2047) + convW (2048..2111) + eq (2112..2143)
// convRef: 1:1 float4 -> ulong map, unit-stride loads/stores, 16 loads in flight.
// ============================================================================
__global__ __launch_bounds__(256) void k_prep(const float* __restrict__ ref,
                                              ushort* __restrict__ refb,
                                              const float* __restrict__ W,
                                              ushort* __restrict__ Wb,
                                              const float* __restrict__ query,
                                              const float* __restrict__ Wq,
                                              float* __restrict__ eq) {
    int bid = blockIdx.x;
    int t = threadIdx.x;
    if (bid < 2048) {
        // ---- ref f32 -> bf16: 2048 blocks x 256 thr x 16 float4 each ----
        const float4* F = (const float4*)ref;
        unsigned long long* U = (unsigned long long*)refb;
        size_t base = (size_t)bid * 4096 + t;
        float4 f[16];
#pragma unroll
        for (int k = 0; k < 16; ++k) f[k] = F[base + k * 256];
#pragma unroll
        for (int k = 0; k < 16; ++k) U[base + k * 256] = pack4(f[k]);
    } else if (bid < 2112) {
        // ---- W_ref f32 -> bf16: 64 blocks x 256 thr x 4 float4 ----
        const float4* F = (const float4*)W;
        unsigned long long* U = (unsigned long long*)Wb;
        int base = (bid - 2048) * 1024 + t;
        float4 f[4];
#pragma unroll
        for (int k = 0; k < 4; ++k) f[k] = F[base + k * 256];
#pragma unroll
        for (int k = 0; k < 4; ++k) U[base + k * 256] = pack4(f[k]);
    } else {
        // ---- eq[b][o] = dot(query[b,:], W_q[o,:]): 32 blocks, 2 o's/thread ----
        __shared__ float q[NH];
        int b = bid - 2112;
        q[t] = query[b * NH + t];
        q[t + 256] = query[b * NH + t + 256];
        __syncthreads();
#pragma unroll
        for (int half = 0; half < 2; ++half) {
            int o = t + half * 256;
            const float4* w = (const float4*)(Wq + (size_t)o * NH);
            float acc = 0.f;
#pragma unroll 4
            for (int i = 0; i < NH / 4; ++i) {
                float4 x = w[i];
                acc += q[4 * i] * x.x + q[4 * i + 1] * x.y + q[4 * i + 2] * x.z + q[4 * i + 3] * x.w;
            }
            eq[b * NH + o] = acc;
        }
    }
}

// ============================================================================
// MAIN GEMM: bf16, global_load_lds staging, tile 128x128, BK=32, 4 waves (2x2),
// dbuf LDS [2][128][32], ONE barrier per K-step.
// ============================================================================
__global__ __launch_bounds__(256, 3) void k_gemm_bf(const ushort* __restrict__ refb,
                                                    const ushort* __restrict__ Wb,
                                                    const float* __restrict__ eq,
                                                    const float* __restrict__ v,
                                                    float* __restrict__ part) {
    __shared__ ushort As[2][128 * 32];
    __shared__ ushort Bs[2][128 * 32];

    int tid = threadIdx.x;
    int lane = tid & 63, wid = tid >> 6;
    int wr = wid >> 1, wc = wid & 1;

    // XCD-aware swizzle: the 4 n-tiles of one m-tile land on the same XCD
    int phys = blockIdx.x;
    int xcd = phys & 7, slot = phys >> 3;         // 8 XCDs x 256 slots
    int mt = xcd * 64 + (slot >> 2);              // 512 m-tiles
    int nt = slot & 3;                            // 4 n-tiles
    int m0 = mt * 128, n0 = nt * 128;
    int b = mt >> 4;                              // 16 m-tiles per batch

    f32x4 acc[4][4];
#pragma unroll
    for (int i = 0; i < 4; ++i)
#pragma unroll
        for (int j = 0; j < 4; ++j) acc[i][j] = (f32x4)(0.f);

    // staging map: wave wid stages chunks cc=wid*2, wid*2+1 (16 rows each).
    int cc = wid * 2;
    int grow = lane >> 2, gcol = (lane & 3) * 8;
    const ushort* aglob = refb + (size_t)(m0 + cc * 16 + grow) * NH + gcol;
    const ushort* bglob = Wb + (size_t)(n0 + cc * 16 + grow) * NH + gcol;

    int lr = lane & 15, kq = lane >> 4;
    int aoff[4], boff[4];
#pragma unroll
    for (int f = 0; f < 4; ++f) {
        aoff[f] = (wr * 64 + f * 16 + lr) * 32 + kq * 8;
        boff[f] = (wc * 64 + f * 16 + lr) * 32 + kq * 8;
    }

#define STAGE(buf, kt)                                      \
    {   gl16(aglob + (kt) * 32, &As[buf][cc * 512]);        \
        gl16(aglob + (kt) * 32 + 16 * NH, &As[buf][(cc + 1) * 512]); \
        gl16(bglob + (kt) * 32, &Bs[buf][cc * 512]);        \
        gl16(bglob + (kt) * 32 + 16 * NH, &Bs[buf][(cc + 1) * 512]); }

#define READ_FRAGS(buf)                                     \
    _Pragma("unroll")                                       \
    for (int f = 0; f < 4; ++f) af[f] = *(const s16x8*)&As[buf][aoff[f]]; \
    _Pragma("unroll")                                       \
    for (int f = 0; f < 4; ++f) bfr[f] = *(const s16x8*)&Bs[buf][boff[f]];

#define DO_MFMA()                                           \
    _Pragma("unroll")                                       \
    for (int fr = 0; fr < 4; ++fr)                          \
        _Pragma("unroll")                                   \
        for (int fc = 0; fc < 4; ++fc)                      \
            acc[fr][fc] = __builtin_amdgcn_mfma_f32_16x16x32_bf16(af[fr], bfr[fc], acc[fr][fc], 0, 0, 0);

    // prologue: tile 0 -> buf0
    STAGE(0, 0)
    __syncthreads();

    for (int t2 = 0; t2 < 8; ++t2) {
        s16x8 af[4], bfr[4];
        int k0 = 2 * t2;
        if (k0 + 1 < 16) STAGE(1, k0 + 1)
        READ_FRAGS(0)
        DO_MFMA()
        __syncthreads();
        if (k0 + 2 < 16) STAGE(0, k0 + 2)
        READ_FRAGS(1)
        DO_MFMA()
        __syncthreads();
    }
#undef STAGE
#undef READ_FRAGS
#undef DO_MFMA

    // epilogue: partial score = sum_{o in tile} v[o]*tanh(e + eq[b][o])
    const float* eqb = eq + b * NH;
    float vv[4], ee[4];
#pragma unroll
    for (int fc = 0; fc < 4; ++fc) {
        int c = n0 + wc * 64 + fc * 16 + lr;
        vv[fc] = v[c];
        ee[fc] = eqb[c];
    }
#pragma unroll
    for (int fr = 0; fr < 4; ++fr) {
#pragma unroll
        for (int reg = 0; reg < 4; ++reg) {
            float s = 0.f;
#pragma unroll
            for (int fc = 0; fc < 4; ++fc) {
                float x = acc[fr][fc][reg] + ee[fc];
                float t = 1.f - 2.f / (__expf(2.f * x) + 1.f);  // tanh
                s += vv[fc] * t;
            }
            s += __shfl_xor(s, 1);
            s += __shfl_xor(s, 2);
            s += __shfl_xor(s, 4);
            s += __shfl_xor(s, 8);
            if (lr == 0) {
                int row = wr * 64 + fr * 16 + kq * 4 + reg;
                part[(size_t)nt * NM + m0 + row] = s;
            }
        }
    }
}

// ============================================================================
// k_smglp: fused softmax + glimpse slice. grid (8 sp, 32 b).
// ============================================================================
__global__ __launch_bounds__(256) void k_smglp(const float* __restrict__ part,
                                               const int* __restrict__ mask,
                                               const ushort* __restrict__ refb,
                                               float* __restrict__ out_sc,
                                               float* __restrict__ glp) {
    int sp = blockIdx.x, b = blockIdx.y;
    int tid = threadIdx.x;
    int lane = tid & 63, wid = tid >> 6;
    __shared__ float red[4];
    __shared__ float asl[256];    // unnormalized exp for rows sp*256..+255
    float sc[8];
    float mx = -3.4e38f;
#pragma unroll
    for (int i = 0; i < 8; ++i) {
        int m = b * NL + i * 256 + tid;
        float s = (part[m] + part[NM + m] + part[2 * NM + m] + part[3 * NM + m]) * SCALE;
        if (mask[m] != 0) s = -1e9f;
        if (sp == 0) out_sc[m] = s;
        sc[i] = s;
        mx = fmaxf(mx, s);
    }
#pragma unroll
    for (int o = 32; o >= 1; o >>= 1) mx = fmaxf(mx, __shfl_xor(mx, o));
    if (lane == 0) red[wid] = mx;
    __syncthreads();
    mx = fmaxf(fmaxf(red[0], red[1]), fmaxf(red[2], red[3]));
    __syncthreads();
    float ls = 0.f;
#pragma unroll
    for (int i = 0; i < 8; ++i) {
        float e = __expf(sc[i] - mx);
        ls += e;
        if (i == sp) asl[tid] = e;   // static i, runtime sp: no reg-array runtime index
    }
#pragma unroll
    for (int o = 32; o >= 1; o >>= 1) ls += __shfl_xor(ls, o);
    if (lane == 0) red[wid] = ls;
    __syncthreads();
    float inv = 1.f / (red[0] + red[1] + red[2] + red[3]);

    // glimpse over this block's 256 rows (refb rows b*NL + sp*256 ..)
    const ushort* rb = refb + ((size_t)b * NL + sp * 256) * NH;
    float2 acc = make_float2(0.f, 0.f);
#pragma unroll 4
    for (int l = 0; l < 256; ++l) {
        float a = asl[l];
        unsigned r = ((const unsigned*)(rb + (size_t)l * NH))[tid];
        acc.x += a * bf2f(r & 0xFFFFu);
        acc.y += a * bf2f(r >> 16);
    }
    acc.x *= inv;
    acc.y *= inv;
    ((float2*)(glp + (size_t)(sp * NB + b) * NH))[tid] = acc;
}

// ---- reduce glimpse partials (8 splits) ----
__global__ __launch_bounds__(256) void k_gred(const float* __restrict__ glp,
                                              float* __restrict__ out_gl) {
    int idx = blockIdx.x * 256 + threadIdx.x;   // 16384 = B*H
    float s = 0.f;
#pragma unroll
    for (int sp = 0; sp < 8; ++sp) s += glp[sp * (NB * NH) + idx];
    out_gl[idx] = s;
}

// ============================================================================
// FALLBACK PATH (ws too small): R2-proven reg-staged f32 GEMM + separate stages
// ============================================================================
#define LDST 36
__global__ __launch_bounds__(256) void k_convW_f(const float* __restrict__ W,
                                                 ushort* __restrict__ Wb) {
    int i = blockIdx.x * 256 + threadIdx.x;
    const float4* s = (const float4*)W;
    float4 a = s[2 * i], c = s[2 * i + 1];
    union { ushort u[8]; int4 v; } p;
    p.u[0] = f2bf(a.x); p.u[1] = f2bf(a.y); p.u[2] = f2bf(a.z); p.u[3] = f2bf(a.w);
    p.u[4] = f2bf(c.x); p.u[5] = f2bf(c.y); p.u[6] = f2bf(c.z); p.u[7] = f2bf(c.w);
    ((int4*)Wb)[i] = p.v;
}
__global__ __launch_bounds__(512) void k_eq_f(const float* __restrict__ query,
                                              const float* __restrict__ Wq,
                                              float* __restrict__ eq) {
    int b = blockIdx.x;
    int o = threadIdx.x;
    __shared__ float q[NH];
    q[o] = query[b * NH + o];
    __syncthreads();
    const float4* w = (const float4*)(Wq + (size_t)o * NH);
    float acc = 0.f;
#pragma unroll 4
    for (int i = 0; i < NH / 4; ++i) {
        float4 x = w[i];
        acc += q[4 * i] * x.x + q[4 * i + 1] * x.y + q[4 * i + 2] * x.z + q[4 * i + 3] * x.w;
    }
    eq[b * NH + o] = acc;
}
__global__ __launch_bounds__(256) void k_gemm_f32(const float* __restrict__ ref,
                                                  const ushort* __restrict__ Wb,
                                                  const float* __restrict__ eq,
                                                  const float* __restrict__ v,
                                                  float* __restrict__ part) {
    __shared__ ushort As[128 * LDST];
    __shared__ ushort Bs[128 * LDST];
    int tid = threadIdx.x;
    int lane = tid & 63, wid = tid >> 6;
    int wr = wid >> 1, wc = wid & 1;
    int phys = blockIdx.x;
    int xcd = phys & 7, slot = phys >> 3;
    int mt = xcd * 64 + (slot >> 2);
    int nt = slot & 3;
    int m0 = mt * 128, n0 = nt * 128;
    int b = mt >> 4;
    f32x4 acc[4][4];
#pragma unroll
    for (int i = 0; i < 4; ++i)
#pragma unroll
        for (int j = 0; j < 4; ++j) acc[i][j] = (f32x4)(0.f);
    int srow = tid >> 1, sks = (tid & 1) * 16;
    const float*  asrc = ref + (size_t)(m0 + srow) * NH + sks;
    const ushort* bsrc = Wb + (size_t)(n0 + srow) * NH + sks;
    int awr = srow * LDST + sks;
    int lr = lane & 15, kq = lane >> 4;
    int aoff[4], boff[4];
#pragma unroll
    for (int f = 0; f < 4; ++f) {
        aoff[f] = (wr * 64 + f * 16 + lr) * LDST + kq * 8;
        boff[f] = (wc * 64 + f * 16 + lr) * LDST + kq * 8;
    }
    float4 pa0, pa1, pa2, pa3;
    int4 pb0, pb1;
    {
        const float* s = asrc;
        pa0 = *(const float4*)(s); pa1 = *(const float4*)(s + 4);
        pa2 = *(const float4*)(s + 8); pa3 = *(const float4*)(s + 12);
        const int4* bs = (const int4*)(bsrc);
        pb0 = bs[0]; pb1 = bs[1];
    }
    for (int kt = 0; kt < 16; ++kt) {
        union { ushort u[8]; int4 v; } p0, p1;
        p0.u[0] = f2bf(pa0.x); p0.u[1] = f2bf(pa0.y); p0.u[2] = f2bf(pa0.z); p0.u[3] = f2bf(pa0.w);
        p0.u[4] = f2bf(pa1.x); p0.u[5] = f2bf(pa1.y); p0.u[6] = f2bf(pa1.z); p0.u[7] = f2bf(pa1.w);
        p1.u[0] = f2bf(pa2.x); p1.u[1] = f2bf(pa2.y); p1.u[2] = f2bf(pa2.z); p1.u[3] = f2bf(pa2.w);
        p1.u[4] = f2bf(pa3.x); p1.u[5] = f2bf(pa3.y); p1.u[6] = f2bf(pa3.z); p1.u[7] = f2bf(pa3.w);
        *(int4*)&As[awr] = p0.v; *(int4*)&As[awr + 8] = p1.v;
        *(int4*)&Bs[awr] = pb0;  *(int4*)&Bs[awr + 8] = pb1;
        __syncthreads();
        if (kt < 15) {
            const float* s = asrc + (kt + 1) * 32;
            pa0 = *(const float4*)(s); pa1 = *(const float4*)(s + 4);
            pa2 = *(const float4*)(s + 8); pa3 = *(const float4*)(s + 12);
            const int4* bs = (const int4*)(bsrc + (kt + 1) * 32);
            pb0 = bs[0]; pb1 = bs[1];
        }
        s16x8 af[4], bfr[4];
#pragma unroll
        for (int f = 0; f < 4; ++f) af[f] = *(const s16x8*)&As[aoff[f]];
#pragma unroll
        for (int f = 0; f < 4; ++f) bfr[f] = *(const s16x8*)&Bs[boff[f]];
        __syncthreads();
#pragma unroll
        for (int fr = 0; fr < 4; ++fr)
#pragma unroll
            for (int fc = 0; fc < 4; ++fc)
                acc[fr][fc] = __builtin_amdgcn_mfma_f32_16x16x32_bf16(af[fr], bfr[fc], acc[fr][fc], 0, 0, 0);
    }
    const float* eqb = eq + b * NH;
    float vv[4], ee[4];
#pragma unroll
    for (int fc = 0; fc < 4; ++fc) {
        int c = n0 + wc * 64 + fc * 16 + lr;
        vv[fc] = v[c]; ee[fc] = eqb[c];
    }
#pragma unroll
    for (int fr = 0; fr < 4; ++fr) {
#pragma unroll
        for (int reg = 0; reg < 4; ++reg) {
            float s = 0.f;
#pragma unroll
            for (int fc = 0; fc < 4; ++fc) {
                float x = acc[fr][fc][reg] + ee[fc];
                float t = 1.f - 2.f / (__expf(2.f * x) + 1.f);
                s += vv[fc] * t;
            }
            s += __shfl_xor(s, 1); s += __shfl_xor(s, 2);
            s += __shfl_xor(s, 4); s += __shfl_xor(s, 8);
            if (lr == 0) {
                int row = wr * 64 + fr * 16 + kq * 4 + reg;
                part[(size_t)nt * NM + m0 + row] = s;
            }
        }
    }
}
__global__ __launch_bounds__(256) void k_softmax_f(const float* __restrict__ part,
                                                   const int* __restrict__ mask,
                                                   float* __restrict__ out_sc,
                                                   float* __restrict__ attn) {
    int b = blockIdx.x;
    int tid = threadIdx.x;
    int lane = tid & 63, wid = tid >> 6;
    __shared__ float red[4];
    float sc[8];
    float mx = -3.4e38f;
#pragma unroll
    for (int i = 0; i < 8; ++i) {
        int m = b * NL + i * 256 + tid;
        float s = (part[m] + part[NM + m] + part[2 * NM + m] + part[3 * NM + m]) * SCALE;
        if (mask[m] != 0) s = -1e9f;
        out_sc[m] = s;
        sc[i] = s;
        mx = fmaxf(mx, s);
    }
#pragma unroll
    for (int o = 32; o >= 1; o >>= 1) mx = fmaxf(mx, __shfl_xor(mx, o));
    if (lane == 0) red[wid] = mx;
    __syncthreads();
    mx = fmaxf(fmaxf(red[0], red[1]), fmaxf(red[2], red[3]));
    __syncthreads();
    float ls = 0.f;
#pragma unroll
    for (int i = 0; i < 8; ++i) {
        float e = __expf(sc[i] - mx);
        sc[i] = e;
        ls += e;
    }
#pragma unroll
    for (int o = 32; o >= 1; o >>= 1) ls += __shfl_xor(ls, o);
    if (lane == 0) red[wid] = ls;
    __syncthreads();
    float inv = 1.f / (red[0] + red[1] + red[2] + red[3]);
#pragma unroll
    for (int i = 0; i < 8; ++i) attn[b * NL + i * 256 + tid] = sc[i] * inv;
}
__global__ __launch_bounds__(256) void k_glp_f32(const float* __restrict__ ref,
                                                 const float* __restrict__ attn,
                                                 float* __restrict__ glp) {
    int sp = blockIdx.x, b = blockIdx.y;
    int tid = threadIdx.x;
    const float* attb = attn + b * NL + sp * 128;
    float2 acc = make_float2(0.f, 0.f);
#pragma unroll 4
    for (int l = 0; l < 128; ++l) {
        float a = attb[l];
        const float2* row = (const float2*)(ref + (size_t)(b * NL + sp * 128 + l) * NH);
        float2 r = row[tid];
        acc.x += a * r.x;
        acc.y += a * r.y;
    }
    ((float2*)(glp + (size_t)(sp * NB + b) * NH))[tid] = acc;
}
__global__ __launch_bounds__(256) void k_gred16(const float* __restrict__ glp,
                                                float* __restrict__ out_gl) {
    int idx = blockIdx.x * 256 + threadIdx.x;
    float s = 0.f;
#pragma unroll
    for (int sp = 0; sp < 16; ++sp) s += glp[sp * (NB * NH) + idx];
    out_gl[idx] = s;
}

extern "C" void kernel_launch(void* const* d_in, const int* in_sizes, int n_in,
                              void* d_out, int out_size, void* d_ws, size_t ws_size,
                              hipStream_t stream) {
    const float* query = (const float*)d_in[0];
    const float* ref   = (const float*)d_in[1];
    const int*   mask  = (const int*)d_in[2];
    const float* W_ref = (const float*)d_in[3];
    const float* W_q   = (const float*)d_in[4];
    const float* v     = (const float*)d_in[5];

    float* out_gl = (float*)d_out;              // 32*512
    float* out_sc = out_gl + NB * NH;           // 32*2048

    char* w = (char*)d_ws;
    ushort* wW  = (ushort*)w;                   // 524288 B @ 0

    if (ws_size >= (size_t)70100000) {
        // MAIN PATH layout
        ushort* refb = (ushort*)(w + 524288);                              // 67,108,864 B
        float* eq    = (float*)(w + 524288 + 67108864);                    // 65,536
        float* part  = (float*)(w + 524288 + 67108864 + 65536);            // 1,048,576
        float* glp   = (float*)(w + 524288 + 67108864 + 65536 + 1048576);  // 524,288 (8 splits)

        k_prep<<<2144, 256, 0, stream>>>(ref, refb, W_ref, wW, query, W_q, eq);
        k_gemm_bf<<<2048, 256, 0, stream>>>(refb, wW, eq, v, part);
        k_smglp<<<dim3(8, NB), 256, 0, stream>>>(part, mask, refb, out_sc, glp);
        k_gred<<<64, 256, 0, stream>>>(glp, out_gl);
    } else {
        // FALLBACK PATH (R2-proven)
        float* eq   = (float*)(w + 524288);
        float* part = (float*)(w + 589824);
        float* attn = (float*)(w + 1638400);
        float* glp  = (float*)(w + 1900544);

        k_convW_f<<<128, 256, 0, stream>>>(W_ref, wW);
        k_eq_f<<<NB, 512, 0, stream>>>(query, W_q, eq);
        k_gemm_f32<<<2048, 256, 0, stream>>>(ref, wW, eq, v, part);
        k_softmax_f<<<NB, 256, 0, stream>>>(part, mask, out_sc, attn);
        k_glp_f32<<<dim3(16, NB), 256, 0, stream>>>(ref, attn, glp);
        k_gred16<<<64, 256, 0, stream>>>(glp, out_gl);
    }
}

// Round 8
// 123.151 us; speedup vs baseline: 1.1844x; 1.1442x over previous
//
#include <hip/hip_runtime.h>
#include <hip/hip_bf16.h>
#include <cstdint>

typedef __attribute__((ext_vector_type(4))) float f32x4;
typedef __attribute__((ext_vector_type(8))) short s16x8;

#define NB   32
#define NL   2048
#define NH   512
#define NM   (NB * NL)          // 65536 rows
#define SCALE 0.04419417382415922f  // 1/sqrt(512)

__device__ __forceinline__ ushort f2bf(float f) {
    __hip_bfloat16 b = __float2bfloat16(f);   // pairs fuse into v_cvt_pk_bf16_f32
    return *reinterpret_cast<ushort*>(&b);
}
__device__ __forceinline__ unsigned long long pack4(float4 f) {
    union { ushort u[4]; unsigned long long v; } p;
    p.u[0] = f2bf(f.x); p.u[1] = f2bf(f.y); p.u[2] = f2bf(f.z); p.u[3] = f2bf(f.w);
    return p.v;
}

// async global->LDS, 16B per lane, dest = wave-uniform base + lane*16
__device__ __forceinline__ void gl16(const ushort* g, ushort* l) {
    __builtin_amdgcn_global_load_lds(
        (const __attribute__((address_space(1))) unsigned int*)g,
        (__attribute__((address_space(3))) unsigned int*)l,
        16, 0, 0);
}

// ============================================================================
// k_pre: convW (blocks 0..63) + eq (blocks 64..95)
// ============================================================================
__global__ __launch_bounds__(256) void k_pre(const float* __restrict__ W,
                                             ushort* __restrict__ Wb,
                                             const float* __restrict__ query,
                                             const float* __restrict__ Wq,
                                             float* __restrict__ eq) {
    int bid = blockIdx.x;
    int t = threadIdx.x;
    if (bid < 64) {
        const float4* F = (const float4*)W;
        unsigned long long* U = (unsigned long long*)Wb;
        int base = bid * 1024 + t;
        float4 f[4];
#pragma unroll
        for (int k = 0; k < 4; ++k) f[k] = F[base + k * 256];
#pragma unroll
        for (int k = 0; k < 4; ++k) U[base + k * 256] = pack4(f[k]);
    } else {
        __shared__ float q[NH];
        int b = bid - 64;
        q[t] = query[b * NH + t];
        q[t + 256] = query[b * NH + t + 256];
        __syncthreads();
#pragma unroll
        for (int half = 0; half < 2; ++half) {
            int o = t + half * 256;
            const float4* w = (const float4*)(Wq + (size_t)o * NH);
            float acc = 0.f;
#pragma unroll 4
            for (int i = 0; i < NH / 4; ++i) {
                float4 x = w[i];
                acc += q[4 * i] * x.x + q[4 * i + 1] * x.y + q[4 * i + 2] * x.z + q[4 * i + 3] * x.w;
            }
            eq[b * NH + o] = acc;
        }
    }
}

// ============================================================================
// k_gemm_full: full-N score GEMM. 1024 blocks x 512 thr.
// BM=64, BN=512 (entire W), BK=32, 16 K-steps.
// 8 waves, wave wid: rows 0..63 x cols wid*64..+64, 4x4 16x16 frags.
// A (f32 ref): reg-staged, cvt->LDS [64][36] padded.  B (bf16 W): gl16, [512][32].
// One barrier per phase. Epilogue: full score rows -> masked -> out_sc (final).
// ============================================================================
__global__ __launch_bounds__(512, 4) void k_gemm_full(const float* __restrict__ ref,
                                                      const ushort* __restrict__ Wb,
                                                      const float* __restrict__ eq,
                                                      const float* __restrict__ v,
                                                      const int* __restrict__ mask,
                                                      float* __restrict__ out_sc) {
    __shared__ ushort Bs[2][512 * 32];   // 64 KB
    __shared__ ushort As[2][64 * 36];    // 9 KB
    __shared__ float sc_red[8][64];      // 2 KB

    int tid = threadIdx.x;
    int lane = tid & 63, wid = tid >> 6;
    int blk = blockIdx.x;
    int m0g = blk << 6;                  // global row base (64 rows/block)
    int b = blk >> 5;                    // batch (2048 rows = 32 blocks)

    f32x4 acc[4][4];
#pragma unroll
    for (int i = 0; i < 4; ++i)
#pragma unroll
        for (int j = 0; j < 4; ++j) acc[i][j] = (f32x4)(0.f);

    // B staging: wave wid stages W rows wid*64..+64, 4 gl16/K-step.
    // per gl16: 16 rows; lane l -> row += l>>2, col8 = (l&3)*8
    const ushort* bglob = Wb + ((size_t)(wid * 64) + (lane >> 2)) * NH + (lane & 3) * 8;
    // A staging: thread t -> row t>>3 (0..63), cols (t&7)*4
    int arow = tid >> 3, acol = (tid & 7) * 4;
    const float* aglob = ref + (size_t)(m0g + arow) * NH + acol;
    int awr = arow * 36 + acol;

    int lr = lane & 15, kq = lane >> 4;
    int aof = lr * 36 + kq * 8;          // + f*16*36 (imm-foldable)
    int bof = (wid * 64 + lr) * 32 + kq * 8;  // + f*16*32

#define STAGE_B(buf, kt)                                                     \
    {   gl16(bglob + (kt) * 32,               &Bs[buf][(wid * 64) * 32]);    \
        gl16(bglob + (kt) * 32 + 16 * NH,     &Bs[buf][(wid * 64 + 16) * 32]); \
        gl16(bglob + (kt) * 32 + 32 * NH,     &Bs[buf][(wid * 64 + 32) * 32]); \
        gl16(bglob + (kt) * 32 + 48 * NH,     &Bs[buf][(wid * 64 + 48) * 32]); }

#define LOAD_A(kt)   pa = *(const float4*)(aglob + (kt) * 32);

#define WRITE_A(buf) { *(unsigned long long*)&As[buf][awr] = pack4(pa); }

#define READ_FRAGS(buf)                                                      \
    _Pragma("unroll")                                                        \
    for (int f = 0; f < 4; ++f) af[f] = *(const s16x8*)&As[buf][aof + f * 16 * 36]; \
    _Pragma("unroll")                                                        \
    for (int f = 0; f < 4; ++f) bfr[f] = *(const s16x8*)&Bs[buf][bof + f * 16 * 32];

#define DO_MFMA()                                                            \
    _Pragma("unroll")                                                        \
    for (int fr = 0; fr < 4; ++fr)                                           \
        _Pragma("unroll")                                                    \
        for (int fc = 0; fc < 4; ++fc)                                       \
            acc[fr][fc] = __builtin_amdgcn_mfma_f32_16x16x32_bf16(af[fr], bfr[fc], acc[fr][fc], 0, 0, 0);

    float4 pa;
    // prologue: K-step 0 -> buf0
    LOAD_A(0)
    WRITE_A(0)
    STAGE_B(0, 0)
    __syncthreads();

    for (int t2 = 0; t2 < 8; ++t2) {
        s16x8 af[4], bfr[4];
        int k0 = 2 * t2;
        // phase A: compute k0 from buf0; stage k0+1 -> buf1 (A write-late)
        if (k0 + 1 < 16) { LOAD_A(k0 + 1) STAGE_B(1, k0 + 1) }
        READ_FRAGS(0)
        DO_MFMA()
        if (k0 + 1 < 16) WRITE_A(1)
        __syncthreads();
        // phase B: compute k0+1 from buf1; stage k0+2 -> buf0
        if (k0 + 2 < 16) { LOAD_A(k0 + 2) STAGE_B(0, k0 + 2) }
        READ_FRAGS(1)
        DO_MFMA()
        if (k0 + 2 < 16) WRITE_A(0)
        __syncthreads();
    }
#undef STAGE_B
#undef LOAD_A
#undef WRITE_A
#undef READ_FRAGS
#undef DO_MFMA

    // ---- epilogue: full score rows ----
    const float* eqb = eq + b * NH;
    float vv[4], ee[4];
#pragma unroll
    for (int fc = 0; fc < 4; ++fc) {
        int c = wid * 64 + fc * 16 + lr;
        vv[fc] = v[c];
        ee[fc] = eqb[c];
    }
#pragma unroll
    for (int fr = 0; fr < 4; ++fr) {
#pragma unroll
        for (int reg = 0; reg < 4; ++reg) {
            float s = 0.f;
#pragma unroll
            for (int fc = 0; fc < 4; ++fc) {
                float x = acc[fr][fc][reg] + ee[fc];
                float t = 1.f - 2.f / (__expf(2.f * x) + 1.f);  // tanh
                s += vv[fc] * t;
            }
            s += __shfl_xor(s, 1);
            s += __shfl_xor(s, 2);
            s += __shfl_xor(s, 4);
            s += __shfl_xor(s, 8);
            if (lr == 0) sc_red[wid][fr * 16 + kq * 4 + reg] = s;
        }
    }
    __syncthreads();
    if (tid < 64) {
        float t = 0.f;
#pragma unroll
        for (int w = 0; w < 8; ++w) t += sc_red[w][tid];
        t *= SCALE;
        int rg = m0g + tid;
        if (mask[rg] != 0) t = -1e9f;
        out_sc[rg] = t;
    }
}

// ============================================================================
// k_smglp: softmax (from final scores) + glimpse slice. grid (16 sp, 32 b).
// f32 ref. Each block: full-row softmax stats + 128-row glimpse partial.
// ============================================================================
__global__ __launch_bounds__(256) void k_smglp(const float* __restrict__ scores,
                                               const float* __restrict__ ref,
                                               float* __restrict__ glp) {
    int sp = blockIdx.x, b = blockIdx.y;
    int tid = threadIdx.x;
    int lane = tid & 63, wid = tid >> 6;
    __shared__ float red[4];
    __shared__ float asl[128];    // unnormalized exp for rows sp*128..+128
    float sc[8];
    float mx = -3.4e38f;
#pragma unroll
    for (int i = 0; i < 8; ++i) {
        sc[i] = scores[b * NL + i * 256 + tid];
        mx = fmaxf(mx, sc[i]);
    }
#pragma unroll
    for (int o = 32; o >= 1; o >>= 1) mx = fmaxf(mx, __shfl_xor(mx, o));
    if (lane == 0) red[wid] = mx;
    __syncthreads();
    mx = fmaxf(fmaxf(red[0], red[1]), fmaxf(red[2], red[3]));
    __syncthreads();
    float ls = 0.f;
#pragma unroll
    for (int i = 0; i < 8; ++i) {
        float e = __expf(sc[i] - mx);
        ls += e;
        // slice sp covers rows [sp*128, sp*128+128) = half of i-block sp>>1
        if (i == (sp >> 1) && (tid >> 7) == (sp & 1)) asl[tid & 127] = e;
    }
#pragma unroll
    for (int o = 32; o >= 1; o >>= 1) ls += __shfl_xor(ls, o);
    if (lane == 0) red[wid] = ls;
    __syncthreads();
    float inv = 1.f / (red[0] + red[1] + red[2] + red[3]);

    const float* rb = ref + ((size_t)b * NL + sp * 128) * NH;
    float2 acc = make_float2(0.f, 0.f);
#pragma unroll 4
    for (int l = 0; l < 128; ++l) {
        float a = asl[l];
        float2 r = ((const float2*)(rb + (size_t)l * NH))[tid];
        acc.x += a * r.x;
        acc.y += a * r.y;
    }
    acc.x *= inv;
    acc.y *= inv;
    ((float2*)(glp + (size_t)(sp * NB + b) * NH))[tid] = acc;
}

// ---- reduce glimpse partials (16 splits) ----
__global__ __launch_bounds__(256) void k_gred(const float* __restrict__ glp,
                                              float* __restrict__ out_gl) {
    int idx = blockIdx.x * 256 + threadIdx.x;   // 16384 = B*H
    float s = 0.f;
#pragma unroll
    for (int sp = 0; sp < 16; ++sp) s += glp[sp * (NB * NH) + idx];
    out_gl[idx] = s;
}

extern "C" void kernel_launch(void* const* d_in, const int* in_sizes, int n_in,
                              void* d_out, int out_size, void* d_ws, size_t ws_size,
                              hipStream_t stream) {
    const float* query = (const float*)d_in[0];
    const float* ref   = (const float*)d_in[1];
    const int*   mask  = (const int*)d_in[2];
    const float* W_ref = (const float*)d_in[3];
    const float* W_q   = (const float*)d_in[4];
    const float* v     = (const float*)d_in[5];

    float* out_gl = (float*)d_out;              // 32*512
    float* out_sc = out_gl + NB * NH;           // 32*2048 (final scores)

    char* w = (char*)d_ws;
    ushort* wW = (ushort*)w;                    // 524,288 B @ 0
    float* eq  = (float*)(w + 524288);          // 65,536 B
    float* glp = (float*)(w + 589824);          // 16*32*512*4 = 1,048,576 B

    k_pre<<<96, 256, 0, stream>>>(W_ref, wW, query, W_q, eq);
    k_gemm_full<<<1024, 512, 0, stream>>>(ref, wW, eq, v, mask, out_sc);
    k_smglp<<<dim3(16, NB), 256, 0, stream>>>(out_sc, ref, glp);
    k_gred<<<64, 256, 0, stream>>>(glp, out_gl);
}